// Round 19
// baseline (70.781 us; speedup 1.0000x reference)
//
#include <hip/hip_runtime.h>
#include <math.h>

#define NN 8192      // nodes
#define FH 128       // hidden
#define NC 16        // clusters
#define HP 132       // padded LDS row
#define CHUNK 32     // nodes per block in node phase (256 blocks)

// ---------------- workspace layout (floats) ----------------
#define WS_CNT   0          // [8192]   zeroed by k_zero_cnt
#define WS_AGG4  8192       // [32768]  zeroed by k_degree
// accumulator region zeroed by k_edge_agg (blocks 0-20):
#define WS_ORAW  40960      // 4 x 2048 replicas
#define WS_SS    49152      // 4 x 256 replicas
#define WS_CA    50176      // 16 x 16
#define WS_CS    50432      // 16 x 16
#define WS_TR    50688      // 16 replicas spread 32 floats (128B) apart
#define WS_DONE  51200      // [32] ints (done counter)
#define WS_END   51328
#define WS_ACC_BEGIN_F4 10240   // 40960/4
#define WS_ACC_COUNT_F4 2592    // (51328-40960)/4

// ---------------- K1: zero cnt only ----------------
__global__ __launch_bounds__(256) void k_zero_cnt(float4* __restrict__ ws) {
    int i = blockIdx.x * blockDim.x + threadIdx.x;   // 8 blocks
    if (i < NN / 4) ws[i] = make_float4(0.f, 0.f, 0.f, 0.f);
}

// ---------------- K2: in-degree (1 edge/thread, 1024x128) + zero agg4 ----------------
__global__ __launch_bounds__(128) void k_degree(const int* __restrict__ ei,
                                                float* __restrict__ ws, int E) {
    int t = threadIdx.x, b = blockIdx.x;             // 1024 blocks x 128
    if (t < 8)    // zero agg4: 1024 blocks x 8 f4 = 32768 floats
        reinterpret_cast<float4*>(ws)[NN / 4 + b * 8 + t] =
            make_float4(0.f, 0.f, 0.f, 0.f);
    int e = b * 128 + t;
    if (e < E) atomicAdd(&ws[WS_CNT + ei[E + e]], 1.0f);
}

// ---------------- K3: agg4 scatter (1 edge/thread, 1024x128) + zero accumulators ----------------
__global__ __launch_bounds__(128) void k_edge_agg(const int* __restrict__ ei,
                                                  const float* __restrict__ x,
                                                  float* __restrict__ ws, int E) {
    int t = threadIdx.x, b = blockIdx.x;             // 1024 blocks x 128
    if (b < 21) {   // zero oraw/ss/ca/cs/tr/done region (2592 f4)
        int i = b * 128 + t;
        if (i < WS_ACC_COUNT_F4)
            reinterpret_cast<float4*>(ws)[WS_ACC_BEGIN_F4 + i] =
                make_float4(0.f, 0.f, 0.f, 0.f);
    }
    int e = b * 128 + t;
    if (e >= E) return;
    int s = ei[e], d = ei[E + e];
    float di = rsqrtf(ws[WS_CNT + s] + 1.0f);
    float4 xv = reinterpret_cast<const float4*>(x)[s];
    float* agg4 = ws + WS_AGG4;
    atomicAdd(&agg4[d * 4 + 0], di * xv.x);
    atomicAdd(&agg4[d * 4 + 1], di * xv.y);
    atomicAdd(&agg4[d * 4 + 2], di * xv.z);
    atomicAdd(&agg4[d * 4 + 3], di * xv.w);
}

// ---------------- K4: fused node pipeline (32 nodes/block, 256 blocks) ----------------
__global__ __launch_bounds__(256) void k_node(const float* __restrict__ x,
                                              const float* __restrict__ W1,
                                              const float* __restrict__ b1,
                                              const float* __restrict__ Wp,
                                              const float* __restrict__ bp,
                                              float* __restrict__ ws,
                                              float* __restrict__ s_out) {
    float* cnt  = ws + WS_CNT;
    float* agg4 = ws + WS_AGG4;
    float* oraw = ws + WS_ORAW;
    float* ssb  = ws + WS_SS;
    float* cab  = ws + WS_CA;
    float* csb  = ws + WS_CS;

    __shared__ float h_lds[CHUNK][HP];
    __shared__ float wpT[NC * HP];
    __shared__ float s_lds[CHUNK][NC];
    __shared__ float z_lds[CHUNK][4];
    __shared__ float c_lds[CHUNK];
    int t = threadIdx.x;
    int b = blockIdx.x;
    int base = b * CHUNK;

    #pragma unroll
    for (int r = 0; r < 8; ++r) {
        int idx = r * 256 + t;             // = f*16 + c
        wpT[(idx & 15) * HP + (idx >> 4)] = Wp[idx];
    }
    if (t < CHUNK) {
        float4 a  = reinterpret_cast<const float4*>(agg4)[base + t];
        float4 xv = reinterpret_cast<const float4*>(x)[base + t];
        float cn = cnt[base + t];
        c_lds[t] = cn;
        float di = rsqrtf(cn + 1.0f);
        z_lds[t][0] = di * fmaf(xv.x, di, a.x);
        z_lds[t][1] = di * fmaf(xv.y, di, a.y);
        z_lds[t][2] = di * fmaf(xv.z, di, a.z);
        z_lds[t][3] = di * fmaf(xv.w, di, a.w);
    }
    __syncthreads();

    int f = t & 127;
    {
        float w0 = W1[f], w1 = W1[128 + f], w2 = W1[256 + f], w3 = W1[384 + f];
        float bb = b1[f];
        int n0 = t >> 7;
        #pragma unroll
        for (int r = 0; r < 16; ++r) {
            int n = n0 + r * 2;
            float v = fmaf(z_lds[n][0], w0, bb);
            v = fmaf(z_lds[n][1], w1, v);
            v = fmaf(z_lds[n][2], w2, v);
            v = fmaf(z_lds[n][3], w3, v);
            h_lds[n][f] = fmaxf(v, 0.0f);
        }
    }
    __syncthreads();

    int c = t & 15, g = t >> 4;
    const float4* wrow = reinterpret_cast<const float4*>(&wpT[c * HP]);
    #pragma unroll
    for (int pass = 0; pass < 2; ++pass) {
        int n = pass * 16 + g;
        const float4* hrow = reinterpret_cast<const float4*>(&h_lds[n][0]);
        float logit = bp[c];
        #pragma unroll 8
        for (int q = 0; q < 32; ++q) {
            float4 hv = hrow[q];
            float4 wv = wrow[q];
            logit = fmaf(hv.x, wv.x, logit);
            logit = fmaf(hv.y, wv.y, logit);
            logit = fmaf(hv.z, wv.z, logit);
            logit = fmaf(hv.w, wv.w, logit);
        }
        float m = logit;
        #pragma unroll
        for (int o = 8; o; o >>= 1) m = fmaxf(m, __shfl_xor(m, o, 16));
        float ex = expf(logit - m);
        float sum = ex;
        #pragma unroll
        for (int o = 8; o; o >>= 1) sum += __shfl_xor(sum, o, 16);
        float sv = ex / sum;
        s_lds[n][c] = sv;
        s_out[(base + n) * NC + c] = sv;   // single copy (d_out); k_adj gathers here
    }
    __syncthreads();

    float acc[8] = {0, 0, 0, 0, 0, 0, 0, 0};
    float acc_ss = 0.0f, acc_ca = 0.0f, acc_cs = 0.0f;
    int ch = t >> 7;
    int cS = t >> 4, kS = t & 15;
    #pragma unroll
    for (int i = 0; i < CHUNK; ++i) {
        float hv = h_lds[i][f];
        const float4* sv = reinterpret_cast<const float4*>(&s_lds[i][0]);
        float4 sa = sv[ch * 2], sb = sv[ch * 2 + 1];
        acc[0] = fmaf(sa.x, hv, acc[0]);
        acc[1] = fmaf(sa.y, hv, acc[1]);
        acc[2] = fmaf(sa.z, hv, acc[2]);
        acc[3] = fmaf(sa.w, hv, acc[3]);
        acc[4] = fmaf(sb.x, hv, acc[4]);
        acc[5] = fmaf(sb.y, hv, acc[5]);
        acc[6] = fmaf(sb.z, hv, acc[6]);
        acc[7] = fmaf(sb.w, hv, acc[7]);
        acc_ss = fmaf(s_lds[i][cS], s_lds[i][kS], acc_ss);
    }
    if (t < NC) {
        #pragma unroll
        for (int i = 0; i < CHUNK; ++i) {
            acc_ca = fmaf(s_lds[i][t], c_lds[i], acc_ca);
            acc_cs += s_lds[i][t];
        }
    }
    int rep = b & 3;
    #pragma unroll
    for (int j = 0; j < 8; ++j)
        atomicAdd(&oraw[rep * 2048 + (ch * 8 + j) * FH + f], acc[j]);
    atomicAdd(&ssb[rep * 256 + cS * NC + kS], acc_ss);
    if (t < NC) {
        int rep16 = b & 15;
        atomicAdd(&cab[rep16 * NC + t], acc_ca);
        atomicAdd(&csb[rep16 * NC + t], acc_cs);
    }
}

__device__ __forceinline__ float selu_f(float x) {
    const float a = 1.6732632423543772f, sc = 1.0507009873554805f;
    return sc * (x > 0.0f ? x : a * (expf(x) - 1.0f));
}

// ---------------- K5: trace-only adjacency + fused sync-free epilogue ----------------
// (full 16x16 out_adj is dead code in the reference -- only its trace feeds spectral)
__global__ __launch_bounds__(256) void k_adj_final(const int* __restrict__ ei,
                                                   const float* __restrict__ s,
                                                   float* __restrict__ ws,
                                                   float* __restrict__ d_out,
                                                   int E, int nblk) {
    float* oraw = ws + WS_ORAW;
    float* ssb  = ws + WS_SS;
    float* cab  = ws + WS_CA;
    float* csb  = ws + WS_CS;
    float* trb  = ws + WS_TR;
    int*   done = (int*)(ws + WS_DONE);
    __shared__ int lastflag;

    int t = threadIdx.x;
    int b = blockIdx.x;
    int e = b * 256 + t;                   // one edge per thread

    float acc = 0.0f;
    if (e < E) {
        int sN = ei[e], dN = ei[E + e];
        const float4* sr = reinterpret_cast<const float4*>(&s[sN * NC]);
        const float4* dr = reinterpret_cast<const float4*>(&s[dN * NC]);
        float4 a0 = sr[0], a1 = sr[1], a2 = sr[2], a3 = sr[3];
        float4 b0 = dr[0], b1 = dr[1], b2 = dr[2], b3 = dr[3];
        acc = a0.x * b0.x + a0.y * b0.y + a0.z * b0.z + a0.w * b0.w;
        acc = fmaf(a1.x, b1.x, acc); acc = fmaf(a1.y, b1.y, acc);
        acc = fmaf(a1.z, b1.z, acc); acc = fmaf(a1.w, b1.w, acc);
        acc = fmaf(a2.x, b2.x, acc); acc = fmaf(a2.y, b2.y, acc);
        acc = fmaf(a2.z, b2.z, acc); acc = fmaf(a2.w, b2.w, acc);
        acc = fmaf(a3.x, b3.x, acc); acc = fmaf(a3.y, b3.y, acc);
        acc = fmaf(a3.z, b3.z, acc); acc = fmaf(a3.w, b3.w, acc);
    }
    #pragma unroll
    for (int o = 32; o; o >>= 1) acc += __shfl_xor(acc, o, 64);
    if ((t & 63) == 0) {
        int wave = (b * 256 + t) >> 6;
        atomicAdd(&trb[(wave & 15) * 32], acc);
    }

    // ---- fenceless done-count: __syncthreads drains this block's atomics ----
    __syncthreads();
    if (t == 0) {
        int prev = __hip_atomic_fetch_add(&done[0], 1, __ATOMIC_RELAXED,
                                          __HIP_MEMORY_SCOPE_AGENT);
        lastflag = (prev == nblk - 1) ? 1 : 0;
    }
    __syncthreads();
    if (!lastflag) return;
    __threadfence();                       // acquire (last block only)

    // ---- sync-free epilogue: 4 waves, no LDS, no __syncthreads ----
    {
        float Ef = (float)E;
        int lane = t & 63, w = t >> 6;
        if (w == 0) {
            float tot[4];
            float fr2 = 0.f;
            #pragma unroll
            for (int j = 0; j < 4; ++j) {
                int i = lane + j * 64;
                float v = ssb[i] + ssb[256 + i] + ssb[512 + i] + ssb[768 + i];
                tot[j] = v;
                fr2 += v * v;
            }
            #pragma unroll
            for (int o = 32; o; o >>= 1) fr2 += __shfl_xor(fr2, o, 64);
            float fro = sqrtf(fr2);
            float o2 = 0.f;
            #pragma unroll
            for (int j = 0; j < 4; ++j) {
                int i = lane + j * 64;
                float d = tot[j] / fro - ((i % 17 == 0) ? 0.25f : 0.f);
                o2 += d * d;
            }
            #pragma unroll
            for (int o = 32; o; o >>= 1) o2 += __shfl_xor(o2, o, 64);
            float ortho = sqrtf(o2);

            float tv = 0.f, ca = 0.f, cs = 0.f;
            if (lane < 16) {
                tv = trb[lane * 32];       // 16 trace replicas
                #pragma unroll
                for (int r = 0; r < 16; ++r) { ca += cab[r * 16 + lane]; cs += csb[r * 16 + lane]; }
            }
            float tr = tv, can = ca * ca, csn = cs * cs;
            #pragma unroll
            for (int o = 32; o; o >>= 1) {
                tr  += __shfl_xor(tr, o, 64);
                can += __shfl_xor(can, o, 64);
                csn += __shfl_xor(csn, o, 64);
            }
            float spectral = -(tr - can / Ef) / Ef;
            float cluster = sqrtf(csn) / (float)NN * 4.0f - 1.0f;
            if (lane == 0) d_out[NC * FH] = spectral + ortho + cluster;
        }

        #pragma unroll
        for (int rr = 0; rr < 4; ++rr) {
            int cR = w + rr * 4;
            int c0 = lane * 2;
            float va = 0.f, vb = 0.f;
            #pragma unroll
            for (int r = 0; r < 4; ++r) {
                float2 vv = *reinterpret_cast<const float2*>(&oraw[r * 2048 + cR * FH + c0]);
                va += vv.x;
                vb += vv.y;
            }
            va = selu_f(va);
            vb = selu_f(vb);
            float mx = fmaxf(va, vb);
            #pragma unroll
            for (int o = 32; o; o >>= 1) mx = fmaxf(mx, __shfl_xor(mx, o, 64));
            float sm = expf(va - mx) + expf(vb - mx);
            #pragma unroll
            for (int o = 32; o; o >>= 1) sm += __shfl_xor(sm, o, 64);
            float ls = mx + logf(sm);
            d_out[cR * FH + c0]     = va - ls;
            d_out[cR * FH + c0 + 1] = vb - ls;
        }
    }
}

extern "C" void kernel_launch(void* const* d_in, const int* in_sizes, int n_in,
                              void* d_out, int out_size, void* d_ws, size_t ws_size,
                              hipStream_t stream) {
    const float* x  = (const float*)d_in[0];
    const float* W1 = (const float*)d_in[1];
    const float* b1 = (const float*)d_in[2];
    const float* Wp = (const float*)d_in[3];
    const float* bp = (const float*)d_in[4];
    const int*   ei = (const int*)d_in[5];
    int E = in_sizes[5] / 2;

    float* ws  = (float*)d_ws;
    float* out = (float*)d_out;           // [0..2047] log_softmax, [2048] loss
    float* s   = out + NC * FH + 1;       // [2049..] assignments (8192 x 16)

    int adj_blocks = (E + 255) / 256;     // 512

    k_zero_cnt<<<8, 256, 0, stream>>>((float4*)d_ws);
    k_degree  <<<(E + 127) / 128, 128, 0, stream>>>(ei, ws, E);
    k_edge_agg<<<(E + 127) / 128, 128, 0, stream>>>(ei, x, ws, E);
    k_node    <<<NN / CHUNK, 256, 0, stream>>>(x, W1, b1, Wp, bp, ws, s);
    k_adj_final<<<adj_blocks, 256, 0, stream>>>(ei, s, ws, out, E, adj_blocks);
}

// Round 20
// 66.298 us; speedup vs baseline: 1.0676x; 1.0676x over previous
//
#include <hip/hip_runtime.h>
#include <math.h>

#define NN 8192      // nodes
#define FH 128       // hidden
#define NC 16        // clusters
#define HP 132       // padded LDS row
#define CHUNK 32     // nodes per block in node phase (256 blocks)

// ---------------- workspace layout (floats) ----------------
#define WS_CNT   0          // [8192]   zeroed by k_zero_cnt
#define WS_AGG4  8192       // [32768]  zeroed by k_degree
// accumulator region zeroed by k_edge_agg (blocks 0-19):
#define WS_ORAW  40960      // 4 x 2048 replicas
#define WS_SS    49152      // 4 x 256 replicas
#define WS_CA    50176      // 16 x 16
#define WS_CS    50432      // 16 x 16
#define WS_TR    50688      // 16 replicas spread 32 floats (128B) apart
#define WS_END   51200
#define WS_ACC_BEGIN_F4 10240   // 40960/4
#define WS_ACC_COUNT_F4 2560    // (51200-40960)/4

// ---------------- K1: zero cnt only ----------------
__global__ __launch_bounds__(256) void k_zero_cnt(float4* __restrict__ ws) {
    int i = blockIdx.x * blockDim.x + threadIdx.x;   // 8 blocks
    if (i < NN / 4) ws[i] = make_float4(0.f, 0.f, 0.f, 0.f);
}

// ---------------- K2: in-degree (1 edge/thread, 1024x128) + zero agg4 ----------------
__global__ __launch_bounds__(128) void k_degree(const int* __restrict__ ei,
                                                float* __restrict__ ws, int E) {
    int t = threadIdx.x, b = blockIdx.x;             // 1024 blocks x 128
    if (t < 8)    // zero agg4: 1024 blocks x 8 f4 = 32768 floats
        reinterpret_cast<float4*>(ws)[NN / 4 + b * 8 + t] =
            make_float4(0.f, 0.f, 0.f, 0.f);
    int e = b * 128 + t;
    if (e < E) atomicAdd(&ws[WS_CNT + ei[E + e]], 1.0f);
}

// ---------------- K3: agg4 scatter (1 edge/thread, 1024x128) + zero accumulators ----------------
__global__ __launch_bounds__(128) void k_edge_agg(const int* __restrict__ ei,
                                                  const float* __restrict__ x,
                                                  float* __restrict__ ws, int E) {
    int t = threadIdx.x, b = blockIdx.x;             // 1024 blocks x 128
    if (b < 20) {   // zero oraw/ss/ca/cs/tr region (2560 f4)
        reinterpret_cast<float4*>(ws)[WS_ACC_BEGIN_F4 + b * 128 + t] =
            make_float4(0.f, 0.f, 0.f, 0.f);
    }
    int e = b * 128 + t;
    if (e >= E) return;
    int s = ei[e], d = ei[E + e];
    float di = rsqrtf(ws[WS_CNT + s] + 1.0f);
    float4 xv = reinterpret_cast<const float4*>(x)[s];
    float* agg4 = ws + WS_AGG4;
    atomicAdd(&agg4[d * 4 + 0], di * xv.x);
    atomicAdd(&agg4[d * 4 + 1], di * xv.y);
    atomicAdd(&agg4[d * 4 + 2], di * xv.z);
    atomicAdd(&agg4[d * 4 + 3], di * xv.w);
}

// ---------------- K4: fused node pipeline (32 nodes/block, 256 blocks) ----------------
__global__ __launch_bounds__(256) void k_node(const float* __restrict__ x,
                                              const float* __restrict__ W1,
                                              const float* __restrict__ b1,
                                              const float* __restrict__ Wp,
                                              const float* __restrict__ bp,
                                              float* __restrict__ ws,
                                              float* __restrict__ s_out) {
    float* cnt  = ws + WS_CNT;
    float* agg4 = ws + WS_AGG4;
    float* oraw = ws + WS_ORAW;
    float* ssb  = ws + WS_SS;
    float* cab  = ws + WS_CA;
    float* csb  = ws + WS_CS;

    __shared__ float h_lds[CHUNK][HP];
    __shared__ float wpT[NC * HP];
    __shared__ float s_lds[CHUNK][NC];
    __shared__ float z_lds[CHUNK][4];
    __shared__ float c_lds[CHUNK];
    int t = threadIdx.x;
    int b = blockIdx.x;
    int base = b * CHUNK;

    #pragma unroll
    for (int r = 0; r < 8; ++r) {
        int idx = r * 256 + t;             // = f*16 + c
        wpT[(idx & 15) * HP + (idx >> 4)] = Wp[idx];
    }
    if (t < CHUNK) {
        float4 a  = reinterpret_cast<const float4*>(agg4)[base + t];
        float4 xv = reinterpret_cast<const float4*>(x)[base + t];
        float cn = cnt[base + t];
        c_lds[t] = cn;
        float di = rsqrtf(cn + 1.0f);
        z_lds[t][0] = di * fmaf(xv.x, di, a.x);
        z_lds[t][1] = di * fmaf(xv.y, di, a.y);
        z_lds[t][2] = di * fmaf(xv.z, di, a.z);
        z_lds[t][3] = di * fmaf(xv.w, di, a.w);
    }
    __syncthreads();

    int f = t & 127;
    {
        float w0 = W1[f], w1 = W1[128 + f], w2 = W1[256 + f], w3 = W1[384 + f];
        float bb = b1[f];
        int n0 = t >> 7;
        #pragma unroll
        for (int r = 0; r < 16; ++r) {
            int n = n0 + r * 2;
            float v = fmaf(z_lds[n][0], w0, bb);
            v = fmaf(z_lds[n][1], w1, v);
            v = fmaf(z_lds[n][2], w2, v);
            v = fmaf(z_lds[n][3], w3, v);
            h_lds[n][f] = fmaxf(v, 0.0f);
        }
    }
    __syncthreads();

    int c = t & 15, g = t >> 4;
    const float4* wrow = reinterpret_cast<const float4*>(&wpT[c * HP]);
    #pragma unroll
    for (int pass = 0; pass < 2; ++pass) {
        int n = pass * 16 + g;
        const float4* hrow = reinterpret_cast<const float4*>(&h_lds[n][0]);
        float logit = bp[c];
        #pragma unroll 8
        for (int q = 0; q < 32; ++q) {
            float4 hv = hrow[q];
            float4 wv = wrow[q];
            logit = fmaf(hv.x, wv.x, logit);
            logit = fmaf(hv.y, wv.y, logit);
            logit = fmaf(hv.z, wv.z, logit);
            logit = fmaf(hv.w, wv.w, logit);
        }
        float m = logit;
        #pragma unroll
        for (int o = 8; o; o >>= 1) m = fmaxf(m, __shfl_xor(m, o, 16));
        float ex = expf(logit - m);
        float sum = ex;
        #pragma unroll
        for (int o = 8; o; o >>= 1) sum += __shfl_xor(sum, o, 16);
        float sv = ex / sum;
        s_lds[n][c] = sv;
        s_out[(base + n) * NC + c] = sv;   // single copy (d_out); k_adj gathers here
    }
    __syncthreads();

    float acc[8] = {0, 0, 0, 0, 0, 0, 0, 0};
    float acc_ss = 0.0f, acc_ca = 0.0f, acc_cs = 0.0f;
    int ch = t >> 7;
    int cS = t >> 4, kS = t & 15;
    #pragma unroll
    for (int i = 0; i < CHUNK; ++i) {
        float hv = h_lds[i][f];
        const float4* sv = reinterpret_cast<const float4*>(&s_lds[i][0]);
        float4 sa = sv[ch * 2], sb = sv[ch * 2 + 1];
        acc[0] = fmaf(sa.x, hv, acc[0]);
        acc[1] = fmaf(sa.y, hv, acc[1]);
        acc[2] = fmaf(sa.z, hv, acc[2]);
        acc[3] = fmaf(sa.w, hv, acc[3]);
        acc[4] = fmaf(sb.x, hv, acc[4]);
        acc[5] = fmaf(sb.y, hv, acc[5]);
        acc[6] = fmaf(sb.z, hv, acc[6]);
        acc[7] = fmaf(sb.w, hv, acc[7]);
        acc_ss = fmaf(s_lds[i][cS], s_lds[i][kS], acc_ss);
    }
    if (t < NC) {
        #pragma unroll
        for (int i = 0; i < CHUNK; ++i) {
            acc_ca = fmaf(s_lds[i][t], c_lds[i], acc_ca);
            acc_cs += s_lds[i][t];
        }
    }
    int rep = b & 3;
    #pragma unroll
    for (int j = 0; j < 8; ++j)
        atomicAdd(&oraw[rep * 2048 + (ch * 8 + j) * FH + f], acc[j]);
    atomicAdd(&ssb[rep * 256 + cS * NC + kS], acc_ss);
    if (t < NC) {
        int rep16 = b & 15;
        atomicAdd(&cab[rep16 * NC + t], acc_ca);
        atomicAdd(&csb[rep16 * NC + t], acc_cs);
    }
}

// ---------------- K5: TRACE-only adjacency, one edge per thread, float4 gathers ----------------
__global__ __launch_bounds__(256) void k_adj(const int* __restrict__ ei,
                                             const float* __restrict__ s,
                                             float* __restrict__ ws, int E) {
    float* trb = ws + WS_TR;

    int t = threadIdx.x;
    int b = blockIdx.x;
    int e = b * 256 + t;                   // one edge per thread

    float acc = 0.0f;
    if (e < E) {
        int sN = ei[e], dN = ei[E + e];
        const float4* sr = reinterpret_cast<const float4*>(&s[sN * NC]);
        const float4* dr = reinterpret_cast<const float4*>(&s[dN * NC]);
        // 8 independent 16B loads, all in flight
        float4 a0 = sr[0], a1 = sr[1], a2 = sr[2], a3 = sr[3];
        float4 b0 = dr[0], b1 = dr[1], b2 = dr[2], b3 = dr[3];
        acc = a0.x * b0.x + a0.y * b0.y + a0.z * b0.z + a0.w * b0.w;
        acc = fmaf(a1.x, b1.x, acc); acc = fmaf(a1.y, b1.y, acc);
        acc = fmaf(a1.z, b1.z, acc); acc = fmaf(a1.w, b1.w, acc);
        acc = fmaf(a2.x, b2.x, acc); acc = fmaf(a2.y, b2.y, acc);
        acc = fmaf(a2.z, b2.z, acc); acc = fmaf(a2.w, b2.w, acc);
        acc = fmaf(a3.x, b3.x, acc); acc = fmaf(a3.y, b3.y, acc);
        acc = fmaf(a3.z, b3.z, acc); acc = fmaf(a3.w, b3.w, acc);
    }
    // wave-reduce 64 edge-dots -> 1 atomic per wave
    #pragma unroll
    for (int o = 32; o; o >>= 1) acc += __shfl_xor(acc, o, 64);
    if ((t & 63) == 0) {
        int wave = (b * 256 + t) >> 6;
        atomicAdd(&trb[(wave & 15) * 32], acc);
    }
}

// ---------------- K6: sync-free epilogue (1 block, 4 waves, no LDS) ----------------
__device__ __forceinline__ float selu_f(float x) {
    const float a = 1.6732632423543772f, sc = 1.0507009873554805f;
    return sc * (x > 0.0f ? x : a * (expf(x) - 1.0f));
}

__global__ __launch_bounds__(256) void k_final(float* __restrict__ ws,
                                               float* __restrict__ d_out, float Ef) {
    float* oraw = ws + WS_ORAW;
    float* ssb  = ws + WS_SS;
    float* cab  = ws + WS_CA;
    float* csb  = ws + WS_CS;
    float* trb  = ws + WS_TR;
    int t = threadIdx.x;
    int lane = t & 63, w = t >> 6;

    if (w == 0) {
        float tot[4];
        float fr2 = 0.f;
        #pragma unroll
        for (int j = 0; j < 4; ++j) {
            int i = lane + j * 64;
            float v = ssb[i] + ssb[256 + i] + ssb[512 + i] + ssb[768 + i];
            tot[j] = v;
            fr2 += v * v;
        }
        #pragma unroll
        for (int o = 32; o; o >>= 1) fr2 += __shfl_xor(fr2, o, 64);
        float fro = sqrtf(fr2);
        float o2 = 0.f;
        #pragma unroll
        for (int j = 0; j < 4; ++j) {
            int i = lane + j * 64;
            float d = tot[j] / fro - ((i % 17 == 0) ? 0.25f : 0.f);
            o2 += d * d;
        }
        #pragma unroll
        for (int o = 32; o; o >>= 1) o2 += __shfl_xor(o2, o, 64);
        float ortho = sqrtf(o2);

        float tv = 0.f, ca = 0.f, cs = 0.f;
        if (lane < 16) {
            tv = trb[lane * 32];           // 16 trace replicas
            #pragma unroll
            for (int r = 0; r < 16; ++r) { ca += cab[r * 16 + lane]; cs += csb[r * 16 + lane]; }
        }
        float tr = tv, can = ca * ca, csn = cs * cs;
        #pragma unroll
        for (int o = 32; o; o >>= 1) {
            tr  += __shfl_xor(tr, o, 64);
            can += __shfl_xor(can, o, 64);
            csn += __shfl_xor(csn, o, 64);
        }
        float spectral = -(tr - can / Ef) / Ef;
        float cluster = sqrtf(csn) / (float)NN * 4.0f - 1.0f;
        if (lane == 0) d_out[NC * FH] = spectral + ortho + cluster;
    }

    #pragma unroll
    for (int rr = 0; rr < 4; ++rr) {
        int cR = w + rr * 4;
        int c0 = lane * 2;
        float va = 0.f, vb = 0.f;
        #pragma unroll
        for (int r = 0; r < 4; ++r) {
            float2 vv = *reinterpret_cast<const float2*>(&oraw[r * 2048 + cR * FH + c0]);
            va += vv.x;
            vb += vv.y;
        }
        va = selu_f(va);
        vb = selu_f(vb);
        float mx = fmaxf(va, vb);
        #pragma unroll
        for (int o = 32; o; o >>= 1) mx = fmaxf(mx, __shfl_xor(mx, o, 64));
        float sm = expf(va - mx) + expf(vb - mx);
        #pragma unroll
        for (int o = 32; o; o >>= 1) sm += __shfl_xor(sm, o, 64);
        float ls = mx + logf(sm);
        d_out[cR * FH + c0]     = va - ls;
        d_out[cR * FH + c0 + 1] = vb - ls;
    }
}

extern "C" void kernel_launch(void* const* d_in, const int* in_sizes, int n_in,
                              void* d_out, int out_size, void* d_ws, size_t ws_size,
                              hipStream_t stream) {
    const float* x  = (const float*)d_in[0];
    const float* W1 = (const float*)d_in[1];
    const float* b1 = (const float*)d_in[2];
    const float* Wp = (const float*)d_in[3];
    const float* bp = (const float*)d_in[4];
    const int*   ei = (const int*)d_in[5];
    int E = in_sizes[5] / 2;

    float* ws  = (float*)d_ws;
    float* out = (float*)d_out;           // [0..2047] log_softmax, [2048] loss
    float* s   = out + NC * FH + 1;       // [2049..] assignments (8192 x 16)

    k_zero_cnt<<<8, 256, 0, stream>>>((float4*)d_ws);
    k_degree  <<<(E + 127) / 128, 128, 0, stream>>>(ei, ws, E);
    k_edge_agg<<<(E + 127) / 128, 128, 0, stream>>>(ei, x, ws, E);
    k_node    <<<NN / CHUNK, 256, 0, stream>>>(x, W1, b1, Wp, bp, ws, s);
    k_adj     <<<(E + 255) / 256, 256, 0, stream>>>(ei, s, ws, E);
    k_final   <<<1, 256, 0, stream>>>(ws, out, (float)E);
}

// Round 21
// 53.735 us; speedup vs baseline: 1.3172x; 1.2338x over previous
//
#include <hip/hip_runtime.h>
#include <math.h>

#define NN 8192      // nodes
#define FH 128       // hidden
#define NC 16        // clusters
#define HP 132       // padded LDS row
#define CHUNK 32     // nodes per block in node phase (256 blocks)

// ---------------- workspace layout (float-indexed; ints stored via cast) ----------------
#define WS_CNT   0          // [8192] int   in-degree counts (zeroed by k_zero)
#define WS_OFF   8192       // [8256] int   CSR offsets (written by k_prefix)
#define WS_CUR   16448      // [8192] int   fill cursors (written by k_prefix)
#define WS_DINV  24640      // [8192] float rsqrt(deg+1)   (written by k_prefix)
#define WS_CSRC  32832      // [131072] int CSR src lists  (written by k_fill)
// accumulator region (zeroed by k_zero):
#define WS_ORAW  163904     // 4 x 2048 replicas
#define WS_SS    172096     // 4 x 256 replicas
#define WS_CA    173120     // 16 x 16
#define WS_CS    173376     // 16 x 16
#define WS_TR    173632     // 16 replicas spread 32 floats apart
#define WS_END   174144
#define WS_ACC_BEGIN_F4 40976   // 163904/4
#define WS_ACC_COUNT_F4 2560    // (174144-163904)/4

// ---------------- K1: zero cnt + accumulator region ----------------
__global__ __launch_bounds__(256) void k_zero(float4* __restrict__ ws) {
    int i = blockIdx.x * blockDim.x + threadIdx.x;   // 18 blocks
    if (i < 2048) ws[i] = make_float4(0.f, 0.f, 0.f, 0.f);                    // cnt
    else if (i < 2048 + WS_ACC_COUNT_F4)
        ws[WS_ACC_BEGIN_F4 + (i - 2048)] = make_float4(0.f, 0.f, 0.f, 0.f);   // accums
}

// ---------------- K2: in-degree counts (int atomics) ----------------
__global__ __launch_bounds__(128) void k_count(const int* __restrict__ ei,
                                               float* __restrict__ ws, int E) {
    int* cnt = (int*)(ws + WS_CNT);
    int e = blockIdx.x * 128 + threadIdx.x;
    if (e < E) atomicAdd(&cnt[ei[E + e]], 1);
}

// ---------------- K3: 1-block prefix scan -> off, cur, dinv ----------------
__global__ __launch_bounds__(256) void k_prefix(float* __restrict__ ws) {
    int* cnt  = (int*)(ws + WS_CNT);
    int* off  = (int*)(ws + WS_OFF);
    int* cur  = (int*)(ws + WS_CUR);
    float* dinv = ws + WS_DINV;
    __shared__ int psum[256];
    int t = threadIdx.x;
    int base = t * 32;
    int local[32];
    int sum = 0;
    #pragma unroll
    for (int k = 0; k < 32; ++k) { local[k] = cnt[base + k]; sum += local[k]; }
    psum[t] = sum;
    __syncthreads();
    // inclusive Hillis-Steele scan over 256 partials
    for (int o = 1; o < 256; o <<= 1) {
        int v = (t >= o) ? psum[t - o] : 0;
        __syncthreads();
        psum[t] += v;
        __syncthreads();
    }
    int run = psum[t] - sum;               // exclusive prefix for this thread's chunk
    #pragma unroll
    for (int k = 0; k < 32; ++k) {
        off[base + k] = run;
        cur[base + k] = run;
        dinv[base + k] = rsqrtf((float)local[k] + 1.0f);
        run += local[k];
    }
    if (t == 255) off[NN] = run;           // = E
}

// ---------------- K4: fill CSR src lists ----------------
__global__ __launch_bounds__(128) void k_fill(const int* __restrict__ ei,
                                              float* __restrict__ ws, int E) {
    int* cur  = (int*)(ws + WS_CUR);
    int* csrc = (int*)(ws + WS_CSRC);
    int e = blockIdx.x * 128 + threadIdx.x;
    if (e >= E) return;
    int s = ei[e], d = ei[E + e];
    int slot = atomicAdd(&cur[d], 1);
    csrc[slot] = s;
}

// ---------------- K5: fused node pipeline with CSR gather (no atomTail on agg) ----------------
__global__ __launch_bounds__(256) void k_node(const float* __restrict__ x,
                                              const float* __restrict__ W1,
                                              const float* __restrict__ b1,
                                              const float* __restrict__ Wp,
                                              const float* __restrict__ bp,
                                              float* __restrict__ ws,
                                              float* __restrict__ s_out) {
    int*   cnti = (int*)(ws + WS_CNT);
    int*   off  = (int*)(ws + WS_OFF);
    int*   csrc = (int*)(ws + WS_CSRC);
    float* dinv = ws + WS_DINV;
    float* oraw = ws + WS_ORAW;
    float* ssb  = ws + WS_SS;
    float* cab  = ws + WS_CA;
    float* csb  = ws + WS_CS;

    __shared__ float h_lds[CHUNK][HP];
    __shared__ float wpT[NC * HP];
    __shared__ float s_lds[CHUNK][NC];
    __shared__ float z_lds[CHUNK][4];
    __shared__ float c_lds[CHUNK];
    int t = threadIdx.x;
    int b = blockIdx.x;
    int base = b * CHUNK;

    #pragma unroll
    for (int r = 0; r < 8; ++r) {
        int idx = r * 256 + t;             // = f*16 + c
        wpT[(idx & 15) * HP + (idx >> 4)] = Wp[idx];
    }

    // ---- gather-aggregate: 8 threads per node walk its CSR slot range ----
    {
        int i = t >> 3, j = t & 7;         // node i in [0,32), lane j in [0,8)
        int o0 = off[base + i], o1 = off[base + i + 1];
        float ax = 0.f, ay = 0.f, az = 0.f, aw = 0.f;
        for (int slot = o0 + j; slot < o1; slot += 8) {
            int sN = csrc[slot];
            float di = dinv[sN];
            float4 xv = reinterpret_cast<const float4*>(x)[sN];
            ax = fmaf(xv.x, di, ax);
            ay = fmaf(xv.y, di, ay);
            az = fmaf(xv.z, di, az);
            aw = fmaf(xv.w, di, aw);
        }
        #pragma unroll
        for (int o = 4; o; o >>= 1) {
            ax += __shfl_down(ax, o, 8);
            ay += __shfl_down(ay, o, 8);
            az += __shfl_down(az, o, 8);
            aw += __shfl_down(aw, o, 8);
        }
        if (j == 0) {
            float cn = (float)cnti[base + i];
            c_lds[i] = cn;
            float dn = dinv[base + i];
            float4 xv = reinterpret_cast<const float4*>(x)[base + i];
            z_lds[i][0] = dn * fmaf(xv.x, dn, ax);
            z_lds[i][1] = dn * fmaf(xv.y, dn, ay);
            z_lds[i][2] = dn * fmaf(xv.z, dn, az);
            z_lds[i][3] = dn * fmaf(xv.w, dn, aw);
        }
    }
    __syncthreads();

    int f = t & 127;
    {
        float w0 = W1[f], w1 = W1[128 + f], w2 = W1[256 + f], w3 = W1[384 + f];
        float bb = b1[f];
        int n0 = t >> 7;
        #pragma unroll
        for (int r = 0; r < 16; ++r) {
            int n = n0 + r * 2;
            float v = fmaf(z_lds[n][0], w0, bb);
            v = fmaf(z_lds[n][1], w1, v);
            v = fmaf(z_lds[n][2], w2, v);
            v = fmaf(z_lds[n][3], w3, v);
            h_lds[n][f] = fmaxf(v, 0.0f);
        }
    }
    __syncthreads();

    int c = t & 15, g = t >> 4;
    const float4* wrow = reinterpret_cast<const float4*>(&wpT[c * HP]);
    #pragma unroll
    for (int pass = 0; pass < 2; ++pass) {
        int n = pass * 16 + g;
        const float4* hrow = reinterpret_cast<const float4*>(&h_lds[n][0]);
        float logit = bp[c];
        #pragma unroll 8
        for (int q = 0; q < 32; ++q) {
            float4 hv = hrow[q];
            float4 wv = wrow[q];
            logit = fmaf(hv.x, wv.x, logit);
            logit = fmaf(hv.y, wv.y, logit);
            logit = fmaf(hv.z, wv.z, logit);
            logit = fmaf(hv.w, wv.w, logit);
        }
        float m = logit;
        #pragma unroll
        for (int o = 8; o; o >>= 1) m = fmaxf(m, __shfl_xor(m, o, 16));
        float ex = expf(logit - m);
        float sum = ex;
        #pragma unroll
        for (int o = 8; o; o >>= 1) sum += __shfl_xor(sum, o, 16);
        float sv = ex / sum;
        s_lds[n][c] = sv;
        s_out[(base + n) * NC + c] = sv;   // single copy (d_out); k_adj gathers here
    }
    __syncthreads();

    float acc[8] = {0, 0, 0, 0, 0, 0, 0, 0};
    float acc_ss = 0.0f, acc_ca = 0.0f, acc_cs = 0.0f;
    int ch = t >> 7;
    int cS = t >> 4, kS = t & 15;
    #pragma unroll
    for (int i = 0; i < CHUNK; ++i) {
        float hv = h_lds[i][f];
        const float4* sv = reinterpret_cast<const float4*>(&s_lds[i][0]);
        float4 sa = sv[ch * 2], sb = sv[ch * 2 + 1];
        acc[0] = fmaf(sa.x, hv, acc[0]);
        acc[1] = fmaf(sa.y, hv, acc[1]);
        acc[2] = fmaf(sa.z, hv, acc[2]);
        acc[3] = fmaf(sa.w, hv, acc[3]);
        acc[4] = fmaf(sb.x, hv, acc[4]);
        acc[5] = fmaf(sb.y, hv, acc[5]);
        acc[6] = fmaf(sb.z, hv, acc[6]);
        acc[7] = fmaf(sb.w, hv, acc[7]);
        acc_ss = fmaf(s_lds[i][cS], s_lds[i][kS], acc_ss);
    }
    if (t < NC) {
        #pragma unroll
        for (int i = 0; i < CHUNK; ++i) {
            acc_ca = fmaf(s_lds[i][t], c_lds[i], acc_ca);
            acc_cs += s_lds[i][t];
        }
    }
    int rep = b & 3;
    #pragma unroll
    for (int j = 0; j < 8; ++j)
        atomicAdd(&oraw[rep * 2048 + (ch * 8 + j) * FH + f], acc[j]);
    atomicAdd(&ssb[rep * 256 + cS * NC + kS], acc_ss);
    if (t < NC) {
        int rep16 = b & 15;
        atomicAdd(&cab[rep16 * NC + t], acc_ca);
        atomicAdd(&csb[rep16 * NC + t], acc_cs);
    }
}

// ---------------- K6: TRACE-only adjacency, one edge per thread, float4 gathers ----------------
__global__ __launch_bounds__(256) void k_adj(const int* __restrict__ ei,
                                             const float* __restrict__ s,
                                             float* __restrict__ ws, int E) {
    float* trb = ws + WS_TR;

    int t = threadIdx.x;
    int b = blockIdx.x;
    int e = b * 256 + t;                   // one edge per thread

    float acc = 0.0f;
    if (e < E) {
        int sN = ei[e], dN = ei[E + e];
        const float4* sr = reinterpret_cast<const float4*>(&s[sN * NC]);
        const float4* dr = reinterpret_cast<const float4*>(&s[dN * NC]);
        float4 a0 = sr[0], a1 = sr[1], a2 = sr[2], a3 = sr[3];
        float4 b0 = dr[0], b1 = dr[1], b2 = dr[2], b3 = dr[3];
        acc = a0.x * b0.x + a0.y * b0.y + a0.z * b0.z + a0.w * b0.w;
        acc = fmaf(a1.x, b1.x, acc); acc = fmaf(a1.y, b1.y, acc);
        acc = fmaf(a1.z, b1.z, acc); acc = fmaf(a1.w, b1.w, acc);
        acc = fmaf(a2.x, b2.x, acc); acc = fmaf(a2.y, b2.y, acc);
        acc = fmaf(a2.z, b2.z, acc); acc = fmaf(a2.w, b2.w, acc);
        acc = fmaf(a3.x, b3.x, acc); acc = fmaf(a3.y, b3.y, acc);
        acc = fmaf(a3.z, b3.z, acc); acc = fmaf(a3.w, b3.w, acc);
    }
    #pragma unroll
    for (int o = 32; o; o >>= 1) acc += __shfl_xor(acc, o, 64);
    if ((t & 63) == 0) {
        int wave = (b * 256 + t) >> 6;
        atomicAdd(&trb[(wave & 15) * 32], acc);
    }
}

// ---------------- K7: sync-free epilogue (1 block, 4 waves, no LDS) ----------------
__device__ __forceinline__ float selu_f(float x) {
    const float a = 1.6732632423543772f, sc = 1.0507009873554805f;
    return sc * (x > 0.0f ? x : a * (expf(x) - 1.0f));
}

__global__ __launch_bounds__(256) void k_final(float* __restrict__ ws,
                                               float* __restrict__ d_out, float Ef) {
    float* oraw = ws + WS_ORAW;
    float* ssb  = ws + WS_SS;
    float* cab  = ws + WS_CA;
    float* csb  = ws + WS_CS;
    float* trb  = ws + WS_TR;
    int t = threadIdx.x;
    int lane = t & 63, w = t >> 6;

    if (w == 0) {
        float tot[4];
        float fr2 = 0.f;
        #pragma unroll
        for (int j = 0; j < 4; ++j) {
            int i = lane + j * 64;
            float v = ssb[i] + ssb[256 + i] + ssb[512 + i] + ssb[768 + i];
            tot[j] = v;
            fr2 += v * v;
        }
        #pragma unroll
        for (int o = 32; o; o >>= 1) fr2 += __shfl_xor(fr2, o, 64);
        float fro = sqrtf(fr2);
        float o2 = 0.f;
        #pragma unroll
        for (int j = 0; j < 4; ++j) {
            int i = lane + j * 64;
            float d = tot[j] / fro - ((i % 17 == 0) ? 0.25f : 0.f);
            o2 += d * d;
        }
        #pragma unroll
        for (int o = 32; o; o >>= 1) o2 += __shfl_xor(o2, o, 64);
        float ortho = sqrtf(o2);

        float tv = 0.f, ca = 0.f, cs = 0.f;
        if (lane < 16) {
            tv = trb[lane * 32];           // 16 trace replicas
            #pragma unroll
            for (int r = 0; r < 16; ++r) { ca += cab[r * 16 + lane]; cs += csb[r * 16 + lane]; }
        }
        float tr = tv, can = ca * ca, csn = cs * cs;
        #pragma unroll
        for (int o = 32; o; o >>= 1) {
            tr  += __shfl_xor(tr, o, 64);
            can += __shfl_xor(can, o, 64);
            csn += __shfl_xor(csn, o, 64);
        }
        float spectral = -(tr - can / Ef) / Ef;
        float cluster = sqrtf(csn) / (float)NN * 4.0f - 1.0f;
        if (lane == 0) d_out[NC * FH] = spectral + ortho + cluster;
    }

    #pragma unroll
    for (int rr = 0; rr < 4; ++rr) {
        int cR = w + rr * 4;
        int c0 = lane * 2;
        float va = 0.f, vb = 0.f;
        #pragma unroll
        for (int r = 0; r < 4; ++r) {
            float2 vv = *reinterpret_cast<const float2*>(&oraw[r * 2048 + cR * FH + c0]);
            va += vv.x;
            vb += vv.y;
        }
        va = selu_f(va);
        vb = selu_f(vb);
        float mx = fmaxf(va, vb);
        #pragma unroll
        for (int o = 32; o; o >>= 1) mx = fmaxf(mx, __shfl_xor(mx, o, 64));
        float sm = expf(va - mx) + expf(vb - mx);
        #pragma unroll
        for (int o = 32; o; o >>= 1) sm += __shfl_xor(sm, o, 64);
        float ls = mx + logf(sm);
        d_out[cR * FH + c0]     = va - ls;
        d_out[cR * FH + c0 + 1] = vb - ls;
    }
}

extern "C" void kernel_launch(void* const* d_in, const int* in_sizes, int n_in,
                              void* d_out, int out_size, void* d_ws, size_t ws_size,
                              hipStream_t stream) {
    const float* x  = (const float*)d_in[0];
    const float* W1 = (const float*)d_in[1];
    const float* b1 = (const float*)d_in[2];
    const float* Wp = (const float*)d_in[3];
    const float* bp = (const float*)d_in[4];
    const int*   ei = (const int*)d_in[5];
    int E = in_sizes[5] / 2;

    float* ws  = (float*)d_ws;
    float* out = (float*)d_out;           // [0..2047] log_softmax, [2048] loss
    float* s   = out + NC * FH + 1;       // [2049..] assignments (8192 x 16)

    k_zero  <<<18, 256, 0, stream>>>((float4*)d_ws);
    k_count <<<(E + 127) / 128, 128, 0, stream>>>(ei, ws, E);
    k_prefix<<<1, 256, 0, stream>>>(ws);
    k_fill  <<<(E + 127) / 128, 128, 0, stream>>>(ei, ws, E);
    k_node  <<<NN / CHUNK, 256, 0, stream>>>(x, W1, b1, Wp, bp, ws, s);
    k_adj   <<<(E + 255) / 256, 256, 0, stream>>>(ei, s, ws, E);
    k_final <<<1, 256, 0, stream>>>(ws, out, (float)E);
}